// Round 4
// baseline (2718.272 us; speedup 1.0000x reference)
//
#include <hip/hip_runtime.h>
#include <hip/hip_bf16.h>

typedef __bf16 bf16;
typedef __bf16 bf16x8 __attribute__((ext_vector_type(8)));
typedef float  f32x4  __attribute__((ext_vector_type(4)));

#define MFMA16(a, b, c) __builtin_amdgcn_mfma_f32_16x16x32_bf16((a), (b), (c), 0, 0, 0)

typedef const __attribute__((address_space(1))) void* gptr_t;
typedef __attribute__((address_space(3))) void* sptr_t;

__device__ __forceinline__ void load_lds16(const bf16* g, bf16* l) {
  __builtin_amdgcn_global_load_lds((gptr_t)g, (sptr_t)l, 16, 0, 0);
}

// ---------------- input dtype detector -------------------------------------
// flag = 1 -> inputs are bf16 ; flag = 0 -> inputs are fp32 (reference dtype).
// (Round-1 NaN already proved fp32; kept as cheap insurance.)
__global__ __launch_bounds__(256) void detect_dtype(const unsigned short* __restrict__ w,
                                                    int* __restrict__ flag) {
  __shared__ int cnt[256];
  int c = 0;
#pragma unroll
  for (int k = 0; k < 16; ++k) {
    unsigned short v = w[(threadIdx.x * 16 + k) * 2];
    int e = (v >> 7) & 0xFF;
    c += (e >= 90 && e <= 130) ? 1 : 0;
  }
  cnt[threadIdx.x] = c;
  __syncthreads();
  if (threadIdx.x == 0) {
    int t = 0;
    for (int i = 0; i < 256; ++i) t += cnt[i];
    *flag = (t > 2048) ? 1 : 0;
  }
}

// ---------------- convert x -> bf16 (either source dtype) ------------------
__global__ __launch_bounds__(256) void convert_to_bf16(const void* __restrict__ in,
                                                       bf16* __restrict__ out,
                                                       const int* __restrict__ flag) {
  const int i0 = (blockIdx.x * 256 + threadIdx.x) * 8;
  if (*flag) {
    *(bf16x8*)(out + i0) = *(const bf16x8*)((const bf16*)in + i0);
  } else {
    const float* p = (const float*)in;
    float4 a = *(const float4*)(p + i0);
    float4 b = *(const float4*)(p + i0 + 4);
    bf16x8 v;
    v[0] = (bf16)a.x; v[1] = (bf16)a.y; v[2] = (bf16)a.z; v[3] = (bf16)a.w;
    v[4] = (bf16)b.x; v[5] = (bf16)b.y; v[6] = (bf16)b.z; v[7] = (bf16)b.w;
    *(bf16x8*)(out + i0) = v;
  }
}

// ---------------- transpose+convert: in [R][C] -> out [C][R] bf16 ----------
__global__ __launch_bounds__(256) void transpose_any(const void* __restrict__ in,
                                                     bf16* __restrict__ out,
                                                     const int* __restrict__ flag,
                                                     int R, int C) {
  __shared__ bf16 t[64][65];
  const int c0 = blockIdx.x * 64, r0 = blockIdx.y * 64;
  const int tid = threadIdx.x;
  const int lc = tid & 63, lr4 = tid >> 6;
  if (*flag) {
    const bf16* p = (const bf16*)in;
#pragma unroll
    for (int i = 0; i < 16; ++i) {
      int r = i * 4 + lr4;
      t[r][lc] = p[(size_t)(r0 + r) * C + c0 + lc];
    }
  } else {
    const float* p = (const float*)in;
#pragma unroll
    for (int i = 0; i < 16; ++i) {
      int r = i * 4 + lr4;
      t[r][lc] = (bf16)p[(size_t)(r0 + r) * C + c0 + lc];
    }
  }
  __syncthreads();
#pragma unroll
  for (int i = 0; i < 16; ++i) {
    int r = i * 4 + lr4;
    out[(size_t)(c0 + r) * R + r0 + lc] = t[lc][r];
  }
}

// ---------------- GEMM: C[M][N] = A[M][K] * Bt[N][K]^T, bf16 in, CT out ----
// m97-verified structure. grid = (N/128, M/128), 256 threads, K % 32 == 0.
template <typename CT>
__global__ __launch_bounds__(256) void gemm_bt(const bf16* __restrict__ A,
                                               const bf16* __restrict__ Bt,
                                               CT* __restrict__ C,
                                               int K, int ldc) {
  __shared__ bf16 a_lds[128 * 32];
  __shared__ bf16 b_lds[128 * 32];
  const int tid = threadIdx.x;
  const int w = tid >> 6, lane = tid & 63, l15 = lane & 15, quad = lane >> 4;
  const int wr = w >> 1, wc = w & 1;
  const int m0 = blockIdx.y * 128, n0 = blockIdx.x * 128;

  const f32x4 fz = {0.f, 0.f, 0.f, 0.f};
  f32x4 acc[4][4];
#pragma unroll
  for (int i = 0; i < 4; ++i)
#pragma unroll
    for (int j = 0; j < 4; ++j) acc[i][j] = fz;

  for (int k0 = 0; k0 < K; k0 += 32) {
#pragma unroll
    for (int i = 0; i < 2; ++i) {
      int c = tid + i * 256;
      int r = c >> 2, kk = c & 3;
      load_lds16(A + (size_t)(m0 + r) * K + k0 + kk * 8, &a_lds[c * 8]);
      load_lds16(Bt + (size_t)(n0 + r) * K + k0 + kk * 8, &b_lds[c * 8]);
    }
    __syncthreads();
    bf16x8 af[4], bfr[4];
#pragma unroll
    for (int mb = 0; mb < 4; ++mb)
      af[mb] = *(const bf16x8*)&a_lds[(wr * 64 + mb * 16 + l15) * 32 + quad * 8];
#pragma unroll
    for (int nb = 0; nb < 4; ++nb)
      bfr[nb] = *(const bf16x8*)&b_lds[(wc * 64 + nb * 16 + l15) * 32 + quad * 8];
#pragma unroll
    for (int mb = 0; mb < 4; ++mb)
#pragma unroll
      for (int nb = 0; nb < 4; ++nb)
        acc[mb][nb] = MFMA16(af[mb], bfr[nb], acc[mb][nb]);
    __syncthreads();
  }

#pragma unroll
  for (int mb = 0; mb < 4; ++mb)
#pragma unroll
    for (int nb = 0; nb < 4; ++nb) {
      int row = m0 + wr * 64 + mb * 16 + quad * 4;
      int col = n0 + wc * 64 + nb * 16 + l15;
#pragma unroll
      for (int r = 0; r < 4; ++r)
        C[(size_t)(row + r) * ldc + col] = (CT)acc[mb][nb][r];
    }
}

// ---------------- simple-correct attention: scores + softmax ----------------
// grid (512, 32): blockIdx.y = b*16+h; wave w of 4 handles query row
// i = blockIdx.x*4 + w. Lane handles j = t*64 + lane. Writes full fp32 attn
// row (p for j<=i, zeros beyond), normalized.
__global__ __launch_bounds__(256) void attn_scores(const bf16* __restrict__ qkv,
                                                   float* __restrict__ attn) {
  const int bh = blockIdx.y;
  const int b = bh >> 4, h = bh & 15;
  const int w = threadIdx.x >> 6, lane = threadIdx.x & 63;
  const int i = blockIdx.x * 4 + w;
  const size_t rowbase = (size_t)b * 2048 * 3072;

  __shared__ float qs[4][64];
  qs[w][lane] = (float)qkv[rowbase + (size_t)i * 3072 + h * 64 + lane];
  __syncthreads();

  const int nj = i + 1;
  const int nblk = (nj + 63) >> 6;
  float sc[32];
  float m = -3e38f;
  for (int t = 0; t < nblk; ++t) {
    const int j = t * 64 + lane;
    float s = -3e38f;
    if (j < nj) {
      const bf16* kr = qkv + rowbase + (size_t)j * 3072 + 1024 + h * 64;
      float acc = 0.f;
#pragma unroll
      for (int d = 0; d < 64; d += 8) {
        bf16x8 kv = *(const bf16x8*)(kr + d);
#pragma unroll
        for (int u = 0; u < 8; ++u) acc += qs[w][d + u] * (float)kv[u];
      }
      s = acc * 0.125f;
    }
    sc[t] = s;
    m = fmaxf(m, s);
  }
#pragma unroll
  for (int off = 1; off < 64; off <<= 1) m = fmaxf(m, __shfl_xor(m, off));

  float ls = 0.f;
  for (int t = 0; t < nblk; ++t) {
    float e = (sc[t] > -1e38f) ? __expf(sc[t] - m) : 0.f;
    sc[t] = e;
    ls += e;
  }
#pragma unroll
  for (int off = 1; off < 64; off <<= 1) ls += __shfl_xor(ls, off);
  const float inv = 1.f / ls;

  float* arow = attn + ((size_t)bh << 22) + (size_t)i * 2048;
  for (int t = 0; t < 32; ++t) {
    const int j = t * 64 + lane;
    float v = (t < nblk) ? sc[t] * inv : 0.f;
    arow[j] = v;
  }
}

// ---------------- simple-correct attention: O = P * V ----------------------
// grid (512, 32): wave = query row i, lane = head dim d. P fp32, V bf16.
__global__ __launch_bounds__(256) void attn_pv(const bf16* __restrict__ qkv,
                                               const float* __restrict__ attn,
                                               bf16* __restrict__ o_ws) {
  const int bh = blockIdx.y;
  const int b = bh >> 4, h = bh & 15;
  const int w = threadIdx.x >> 6, lane = threadIdx.x & 63;
  const int i = blockIdx.x * 4 + w;
  const size_t rowbase = (size_t)b * 2048 * 3072;

  const float* arow = attn + ((size_t)bh << 22) + (size_t)i * 2048;
  const bf16* vcol = qkv + rowbase + 2048 + h * 64 + lane;

  float o = 0.f;
  int j = 0;
  for (; j + 4 <= i + 1; j += 4) {
    float4 p = *(const float4*)(arow + j);
    o += p.x * (float)vcol[(size_t)j * 3072];
    o += p.y * (float)vcol[(size_t)(j + 1) * 3072];
    o += p.z * (float)vcol[(size_t)(j + 2) * 3072];
    o += p.w * (float)vcol[(size_t)(j + 3) * 3072];
  }
  for (; j <= i; ++j) o += arow[j] * (float)vcol[(size_t)j * 3072];

  o_ws[((size_t)b * 2048 + i) * 1024 + h * 64 + lane] = (bf16)o;
}

// ---------------- launch ----------------------------------------------------
extern "C" void kernel_launch(void* const* d_in, const int* in_sizes, int n_in,
                              void* d_out, int out_size, void* d_ws, size_t ws_size,
                              hipStream_t stream) {
  const void* x_raw = d_in[0];  // [2,2048,1024] fp32
  const void* w_qkv = d_in[1];  // [1024,3072]   fp32
  const void* w_out = d_in[2];  // [1024,1024]   fp32
  float* out  = (float*)d_out;               // [2,2048,1024] fp32
  float* attn = out + 4194304;               // [2,16,2048,2048] fp32

  // workspace layout (bf16 elements), ~40 MB total
  bf16* ws     = (bf16*)d_ws;
  bf16* qkv_ws = ws;             // [4096][3072]            (24 MB)
  bf16* wqkvT  = ws + 12582912;  // [3072][1024]            (6 MB)
  bf16* woT    = ws + 15728640;  // [1024][1024]            (2 MB)
  bf16* x_bf   = ws + 16777216;  // [4096][1024]            (8 MB)
  bf16* o_ws   = x_bf;           // aliases x_bf (disjoint lifetime)
  int*  flag   = (int*)(ws + 20971520);

  detect_dtype<<<1, 256, 0, stream>>>((const unsigned short*)w_qkv, flag);
  convert_to_bf16<<<2048, 256, 0, stream>>>(x_raw, x_bf, flag);
  transpose_any<<<dim3(48, 16), 256, 0, stream>>>(w_qkv, wqkvT, flag, 1024, 3072);
  transpose_any<<<dim3(16, 16), 256, 0, stream>>>(w_out, woT, flag, 1024, 1024);
  // qkv = x @ W_qkv : [4096][3072] bf16
  gemm_bt<bf16><<<dim3(24, 32), 256, 0, stream>>>(x_bf, wqkvT, qkv_ws, 1024, 3072);
  // attn = softmax(mask(Q K^T / 8))  (fp32 out)
  attn_scores<<<dim3(512, 32), 256, 0, stream>>>(qkv_ws, attn);
  // o = attn @ V
  attn_pv<<<dim3(512, 32), 256, 0, stream>>>(qkv_ws, attn, o_ws);
  // out = o @ W_out  (fp32 out)
  gemm_bt<float><<<dim3(8, 32), 256, 0, stream>>>(o_ws, woT, out, 1024, 1024);
}